// Round 9
// baseline (1112.186 us; speedup 1.0000x reference)
//
#include <hip/hip_runtime.h>
#include <hip/hip_bf16.h>
#include <math.h>

typedef __hip_bfloat16 bf16;
typedef __attribute__((ext_vector_type(8))) short short8v;   // 8 bf16 = 4 VGPR
typedef __attribute__((ext_vector_type(4))) float f32x4;

#define NBATCH 4
#define NPTS   8192
#define TOTPTS 32768
#define DIM    128
#define DOUT   256
#define KNN    16

__device__ __forceinline__ float b2f(bf16 x) { return __bfloat162float(x); }
__device__ __forceinline__ bf16 f2b(float x) { return __float2bfloat16(x); }

__device__ __forceinline__ float rsum32(float v) {
#pragma unroll
  for (int o = 16; o; o >>= 1) v += __shfl_down(v, o, 32);
  return v;
}

// ---------------------------------------------------------------------------
// Pack xyz -> (x, y, z, |p|^2) float4. xyzw parked in the AOUT region of
// d_out (read by knn/pos, fully overwritten later by attn).
// ---------------------------------------------------------------------------
__global__ __launch_bounds__(256) void pack_kernel(const float* __restrict__ xyz,
                                                   float4* __restrict__ xyzw) {
  const int p = blockIdx.x * 256 + threadIdx.x;
  const float x = xyz[3 * p], y = xyz[3 * p + 1], z = xyz[3 * p + 2];
  xyzw[p] = make_float4(x, y, z, x * x + y * y + z * z);
}

// ---------------------------------------------------------------------------
// Segmented insert for KNN v4 (round-5 proven): top-16 of query S in lanes
// [16S,16S+15], slot = lane&15 ascending. Stable jax.lax.top_k semantics.
// ---------------------------------------------------------------------------
template <int S>
__device__ __forceinline__ void ins16(float d2, int g, int lane, int seg,
                                      float& bd, int& bi, float& tmax) {
  unsigned long long mask = __ballot(d2 < tmax);
  while (mask) {                          // wave-uniform loop
    const int l = __builtin_ctzll(mask);
    mask &= mask - 1;
    const float dl = __int_as_float(
        __builtin_amdgcn_readlane(__float_as_int(d2), l));
    if (dl < tmax) {                      // re-check vs tightened threshold
      const int il = g + l;
      const bool keep = bd <= dl;
      const float pd = __shfl_up(bd, 1, 16);    // segmented shift
      const int   pi = __shfl_up(bi, 1, 16);
      const bool fromPrev = ((lane & 15) > 0) && (pd > dl);
      const float nbd = keep ? bd : (fromPrev ? pd : dl);
      const int   nbi = keep ? bi : (fromPrev ? pi : il);
      bd = (seg == S) ? nbd : bd;
      bi = (seg == S) ? nbi : bi;
      tmax = __int_as_float(
          __builtin_amdgcn_readlane(__float_as_int(bd), S * 16 + 15));
    }
  }
}

// ---------------------------------------------------------------------------
// wprep_qkv: transpose Wq/Wk/Wv f32[k][c] -> SPLIT bf16 pairs (hi, lo) in
// MFMA B layout [c][k]. Outputs in the AOUT scratch (read-only during the
// fused kernel; overwritten later by attn).
// ---------------------------------------------------------------------------
__global__ __launch_bounds__(256) void wprep_qkv_kernel(
    const float* __restrict__ Wq, const float* __restrict__ Wk,
    const float* __restrict__ Wv,
    bf16* __restrict__ Wqh, bf16* __restrict__ Wql,
    bf16* __restrict__ Wkh, bf16* __restrict__ Wkl,
    bf16* __restrict__ Wvh, bf16* __restrict__ Wvl) {
  const int t = blockIdx.x * 256 + threadIdx.x;   // [0, 12288)
  const int m = t >> 12;
  const int rem = t & 4095;
  const int c = rem >> 4, k8 = (rem & 15) * 8;
  const float* src = (m == 0) ? Wq : (m == 1) ? Wk : Wv;
  bf16* dh = (m == 0) ? Wqh : (m == 1) ? Wkh : Wvh;
  bf16* dl = (m == 0) ? Wql : (m == 1) ? Wkl : Wvl;
#pragma unroll
  for (int j = 0; j < 8; j++) {
    const float x = src[(k8 + j) * 256 + c];
    const bf16 hi = f2b(x);
    dh[c * 128 + k8 + j] = hi;
    dl[c * 128 + k8 + j] = f2b(x - b2f(hi));
  }
}

// ---------------------------------------------------------------------------
// Fused KNN || proj-MFMA (round 9). Round 6's knn||proj fusion failed because
// both were VALU-bound (VALU work conserved). proj v2 moved its bulk to the
// MFMA pipe (round 8), so the two kernels now stress complementary pipes
// (m114: MFMA-wave + VALU-wave co-schedule at max, not sum). 4096 blocks:
// even bid -> knn (2048), odd bid -> proj (2048), interleaved for mixed
// residency. Bodies byte-identical to round 8.
// ---------------------------------------------------------------------------
#define PR  16
#define PCP 136
__global__ __launch_bounds__(256) void knp_fused_kernel(
    const float4* __restrict__ xyzw, unsigned short* __restrict__ knn_out,
    const float* __restrict__ feat,
    const bf16* __restrict__ Wqh, const bf16* __restrict__ Wql,
    const bf16* __restrict__ Wkh, const bf16* __restrict__ Wkl,
    const bf16* __restrict__ Wvh, const bf16* __restrict__ Wvl,
    const float* __restrict__ bq, const float* __restrict__ bk,
    const float* __restrict__ bv,
    const float* __restrict__ g1, const float* __restrict__ b1,
    bf16* __restrict__ Q, bf16* __restrict__ Kf, bf16* __restrict__ Vf,
    float* __restrict__ skip) {
  __shared__ float fS[PR][DIM];               // proj branch only
  __shared__ bf16 fh[PR][PCP], fl[PR][PCP];
  __shared__ bf16 lh[PR][PCP], ll[PR][PCP];
  const int bid = blockIdx.x;
  const int tid = threadIdx.x;

  if ((bid & 1) == 0) {
    // ------------------------- KNN body (v4, proven) ----------------------
    const int kid  = bid >> 1;
    const int wid  = tid >> 6;
    const int lane = tid & 63;
    const int seg  = lane >> 4;
    const int q0 = (kid * 4 + wid) * 4;
    const int b = q0 >> 13;
    const float4* cb = xyzw + (size_t)b * NPTS;

    const float4 mA = xyzw[q0 + 0];
    const float4 mB = xyzw[q0 + 1];
    const float4 mC = xyzw[q0 + 2];
    const float4 mD = xyzw[q0 + 3];

    float bd = INFINITY;
    int   bi = 0x7fff;
    float tA = INFINITY, tB = INFINITY, tC = INFINITY, tD = INFINITY;

    for (int g = 0; g < NPTS; g += 64) {
      const float4 t = cb[g + lane];
      const float dA = mA.w + t.w - 2.f * (mA.x * t.x + mA.y * t.y + mA.z * t.z);
      const float dB = mB.w + t.w - 2.f * (mB.x * t.x + mB.y * t.y + mB.z * t.z);
      const float dC = mC.w + t.w - 2.f * (mC.x * t.x + mC.y * t.y + mC.z * t.z);
      const float dD = mD.w + t.w - 2.f * (mD.x * t.x + mD.y * t.y + mD.z * t.z);
      ins16<0>(dA, g, lane, seg, bd, bi, tA);
      ins16<1>(dB, g, lane, seg, bd, bi, tB);
      ins16<2>(dC, g, lane, seg, bd, bi, tC);
      ins16<3>(dD, g, lane, seg, bd, bi, tD);
    }
    knn_out[(size_t)q0 * KNN + lane] = (unsigned short)bi;
    return;
  }

  // ------------------- proj body (v2 MFMA split-bf16, proven) -------------
  const size_t r0 = (size_t)(bid >> 1) * PR;

  {
    const float4* src = (const float4*)(feat + r0 * DIM);
    float4* dst = (float4*)&fS[0][0];
#pragma unroll
    for (int i = 0; i < 2; i++) dst[tid + i * 256] = src[tid + i * 256];
  }
  __syncthreads();

  {
    const int r = tid >> 4, j = tid & 15;
    float v[8];
    float s = 0.f;
#pragma unroll
    for (int i = 0; i < 8; i++) { v[i] = fS[r][j * 8 + i]; s += v[i]; }
#pragma unroll
    for (int o = 8; o; o >>= 1) s += __shfl_down(s, o, 16);
    const float mu = __shfl(s, 0, 16) * (1.f / 128.f);
    float ss = 0.f;
#pragma unroll
    for (int i = 0; i < 8; i++) { const float d = v[i] - mu; ss += d * d; }
#pragma unroll
    for (int o = 8; o; o >>= 1) ss += __shfl_down(ss, o, 16);
    const float rsd = rsqrtf(__shfl(ss, 0, 16) * (1.f / 128.f) + 1e-5f);
#pragma unroll
    for (int i = 0; i < 8; i++) {
      const int c = j * 8 + i;
      const bf16 hv = f2b(v[i]);
      fh[r][c] = hv;
      fl[r][c] = f2b(v[i] - b2f(hv));
      const float lnv = (v[i] - mu) * rsd * g1[c] + b1[c];
      const bf16 lhv = f2b(lnv);
      lh[r][c] = lhv;
      ll[r][c] = f2b(lnv - b2f(lhv));
    }
  }
  __syncthreads();

  const int w    = tid >> 6;
  const int lane = tid & 63;
  const int g    = lane >> 4, lr = lane & 15;
  const int cw   = w * 64;
  f32x4 qa[4], ka[4], va[4], sa[4];
#pragma unroll
  for (int t = 0; t < 4; t++) {
    qa[t] = (f32x4){0.f, 0.f, 0.f, 0.f};
    ka[t] = qa[t]; va[t] = qa[t]; sa[t] = qa[t];
  }
#pragma unroll
  for (int s = 0; s < 4; s++) {
    const int k0 = s * 32 + g * 8;
    const short8v ah = *(const short8v*)&fh[lr][k0];
    const short8v al = *(const short8v*)&fl[lr][k0];
    const short8v nh = *(const short8v*)&lh[lr][k0];
    const short8v nl = *(const short8v*)&ll[lr][k0];
#pragma unroll
    for (int t = 0; t < 4; t++) {
      const int c = cw + 16 * t + lr;
      const short8v wqh = *(const short8v*)&Wqh[c * 128 + k0];
      const short8v wql = *(const short8v*)&Wql[c * 128 + k0];
      const short8v wkh = *(const short8v*)&Wkh[c * 128 + k0];
      const short8v wkl = *(const short8v*)&Wkl[c * 128 + k0];
      const short8v wvh = *(const short8v*)&Wvh[c * 128 + k0];
      const short8v wvl = *(const short8v*)&Wvl[c * 128 + k0];
      qa[t] = __builtin_amdgcn_mfma_f32_16x16x32_bf16(ah, wqh, qa[t], 0, 0, 0);
      qa[t] = __builtin_amdgcn_mfma_f32_16x16x32_bf16(ah, wql, qa[t], 0, 0, 0);
      qa[t] = __builtin_amdgcn_mfma_f32_16x16x32_bf16(al, wqh, qa[t], 0, 0, 0);
      ka[t] = __builtin_amdgcn_mfma_f32_16x16x32_bf16(ah, wkh, ka[t], 0, 0, 0);
      ka[t] = __builtin_amdgcn_mfma_f32_16x16x32_bf16(ah, wkl, ka[t], 0, 0, 0);
      ka[t] = __builtin_amdgcn_mfma_f32_16x16x32_bf16(al, wkh, ka[t], 0, 0, 0);
      va[t] = __builtin_amdgcn_mfma_f32_16x16x32_bf16(ah, wvh, va[t], 0, 0, 0);
      va[t] = __builtin_amdgcn_mfma_f32_16x16x32_bf16(ah, wvl, va[t], 0, 0, 0);
      va[t] = __builtin_amdgcn_mfma_f32_16x16x32_bf16(al, wvh, va[t], 0, 0, 0);
      sa[t] = __builtin_amdgcn_mfma_f32_16x16x32_bf16(nh, wqh, sa[t], 0, 0, 0);
      sa[t] = __builtin_amdgcn_mfma_f32_16x16x32_bf16(nh, wql, sa[t], 0, 0, 0);
      sa[t] = __builtin_amdgcn_mfma_f32_16x16x32_bf16(nl, wqh, sa[t], 0, 0, 0);
    }
  }

#pragma unroll
  for (int t = 0; t < 4; t++) {
    const int c = cw + 16 * t + lr;
    const float bqv = bq[c], bkv = bk[c], bvv = bv[c];
#pragma unroll
    for (int e = 0; e < 4; e++) {
      const size_t o = (r0 + 4 * g + e) * DOUT + c;
      Q[o]    = f2b(qa[t][e] + bqv);
      Kf[o]   = f2b(ka[t][e] + bkv);
      Vf[o]   = f2b(va[t][e] + bvv);
      skip[o] = sa[t][e] + bqv;
    }
  }
}

// ---------------------------------------------------------------------------
// pos_kernel (round-2 proven): pos-MLP hoisted out of attn.
// ---------------------------------------------------------------------------
__global__ __launch_bounds__(256) void pos_kernel(
    const float4* __restrict__ xyzw, const unsigned short* __restrict__ knn_in,
    const float* __restrict__ Wp1, const float* __restrict__ bp1,
    const float* __restrict__ Wp2, const float* __restrict__ bp2,
    bf16* __restrict__ posG) {
  __shared__ float h1S[4][16][64];        // 16 KB
  const int wid = threadIdx.x >> 6, lane = threadIdx.x & 63;
  const int p = blockIdx.x * 4 + wid;
  const int b = p >> 13, n = p & (NPTS - 1);
  const float4* cb = xyzw + (size_t)b * NPTS;
  const float4 me = cb[n];

  float rx = 0.f, ry = 0.f, rz = 0.f;
  if (lane < 16) {
    const int idx = knn_in[(size_t)p * KNN + lane];
    const float4 t = cb[idx];
    rx = t.x - me.x; ry = t.y - me.y; rz = t.z - me.z;
  }
  const float w0 = Wp1[lane], w1 = Wp1[64 + lane], w2 = Wp1[128 + lane];
  const float bb1 = bp1[lane], bb2 = bp2[lane];
#pragma unroll
  for (int k = 0; k < 16; k++) {
    const float r0 = __shfl(rx, k, 64);
    const float r1 = __shfl(ry, k, 64);
    const float r2 = __shfl(rz, k, 64);
    h1S[wid][k][lane] = fmaxf(bb1 + r0 * w0 + r1 * w1 + r2 * w2, 0.f);
  }
  __syncthreads();

  float acc[16];
#pragma unroll
  for (int k = 0; k < 16; k++) acc[k] = bb2;
  for (int jq = 0; jq < 16; jq++) {
    const float w2a = Wp2[(jq * 4 + 0) * 64 + lane];
    const float w2b = Wp2[(jq * 4 + 1) * 64 + lane];
    const float w2c = Wp2[(jq * 4 + 2) * 64 + lane];
    const float w2d = Wp2[(jq * 4 + 3) * 64 + lane];
#pragma unroll
    for (int k = 0; k < 16; k++) {
      const float4 h = *(const float4*)&h1S[wid][k][jq * 4];  // broadcast b128
      acc[k] += h.x * w2a + h.y * w2b + h.z * w2c + h.w * w2d;
    }
  }
#pragma unroll
  for (int k = 0; k < 16; k++)
    posG[((size_t)p * KNN + k) * 64 + lane] = f2b(acc[k]);
}

// ---------------------------------------------------------------------------
// Attention v3 (round-2 proven).
// ---------------------------------------------------------------------------
__global__ __launch_bounds__(256) void attn_kernel(
    const unsigned short* __restrict__ knn_in,
    bf16* __restrict__ QOA, const bf16* __restrict__ Kf, const bf16* __restrict__ Vf,
    const bf16* __restrict__ posG,
    float* __restrict__ AOUT) {
  __shared__ int nidxS[16];
  const int tid  = threadIdx.x;
  const int w    = tid >> 6;
  const int lane = tid & 63;
  const int p = blockIdx.x;
  const int b = p >> 13, n = p & (NPTS - 1);

  if (tid < 16) nidxS[tid] = knn_in[(size_t)p * KNN + tid];
  const float qreg = b2f(QOA[(size_t)p * DOUT + tid]);
  __syncthreads();

  float kreg[16], vreg[16], posr[16];
  const size_t rowbase = (size_t)b * NPTS;
  const bf16* pg = posG + (size_t)p * KNN * 64 + lane;
#pragma unroll
  for (int k = 0; k < 16; k++) {
    const size_t row = (rowbase + (size_t)nidxS[k]) * DOUT + tid;
    kreg[k] = b2f(Kf[row]);
    vreg[k] = b2f(Vf[row]);
    posr[k] = b2f(pg[k * 64]);
  }

  float lg[16];
#pragma unroll
  for (int k = 0; k < 16; k++) lg[k] = qreg * (kreg[k] + posr[k]);
#pragma unroll
  for (int o = 32; o; o >>= 1) {
#pragma unroll
    for (int k = 0; k < 16; k++) lg[k] += __shfl_xor(lg[k], o, 64);
  }
  float m = -INFINITY;
#pragma unroll
  for (int k = 0; k < 16; k++) { lg[k] *= 0.125f; m = fmaxf(m, lg[k]); }
  float sum = 0.f;
#pragma unroll
  for (int k = 0; k < 16; k++) { lg[k] = expf(lg[k] - m); sum += lg[k]; }
  const float inv = 1.f / sum;
#pragma unroll
  for (int k = 0; k < 16; k++) lg[k] *= inv;
  float av = 0.f;
#pragma unroll
  for (int k = 0; k < 16; k++) if (lane == k) av = lg[k];
  if (lane < 16)
    AOUT[(((size_t)b * 4 + w) * NPTS + n) * KNN + lane] = av;
  float o = 0.f;
#pragma unroll
  for (int k = 0; k < 16; k++) o += lg[k] * (vreg[k] + posr[k]);
  QOA[(size_t)p * DOUT + tid] = f2b(o);
}

// ---------------------------------------------------------------------------
// wprep: one-time transpose+convert Wf1/Wf2 f32[k][c] -> bf16 Wt[c][k].
// ---------------------------------------------------------------------------
__global__ __launch_bounds__(256) void wprep_kernel(
    const float* __restrict__ Wf1, const float* __restrict__ Wf2,
    bf16* __restrict__ Wt1, bf16* __restrict__ Wt2) {
  const int t = blockIdx.x * 256 + threadIdx.x;          // [0, 16384)
  const float* src = (t & 8192) ? Wf2 : Wf1;
  bf16*        dst = (t & 8192) ? Wt2 : Wt1;
  const int rem = t & 8191;
  const int c = rem >> 5, k8 = (rem & 31) * 8;
#pragma unroll
  for (int j = 0; j < 8; j++)
    dst[c * 256 + k8 + j] = f2b(src[(k8 + j) * 256 + c]);
}

// ---------------------------------------------------------------------------
// FFN v4 (round-7 proven): MFMA, 16 rows/block, aliased LDS, LN2 + residual.
// ---------------------------------------------------------------------------
#define FRB 16
#define FCP 264
__global__ __launch_bounds__(256) void ffn_kernel(
    const bf16* __restrict__ OA,
    const bf16* __restrict__ Wt1, const float* __restrict__ bf1,
    const bf16* __restrict__ Wt2, const float* __restrict__ bf2,
    const float* __restrict__ g2, const float* __restrict__ b2p,
    float* __restrict__ out) {
  __shared__ float zs[FRB][FCP];          // 16896 B; aliased as xs|ys (bf16)
  __shared__ float mu16[FRB], rs16[FRB];
  bf16* base = (bf16*)&zs[0][0];
  const int ysoff = FRB * FCP;
  const int tid  = threadIdx.x;
  const int w    = tid >> 6;
  const int lane = tid & 63;
  const int g    = lane >> 4, lr = lane & 15;
  const int cw   = w * 64;
  const size_t r0 = (size_t)blockIdx.x * FRB;

  {
    const short8v* src = (const short8v*)(OA + r0 * DOUT);
#pragma unroll
    for (int i = 0; i < 2; i++) {
      const int ch = tid + i * 256;
      const int row = ch >> 5, c8 = (ch & 31) * 8;
      *(short8v*)&base[row * FCP + c8] = src[ch];
    }
  }
  __syncthreads();

  f32x4 a0 = {0.f, 0.f, 0.f, 0.f}, a1 = a0, a2 = a0, a3 = a0;

#define GEMM8(OFF, WT)                                                         \
  _Pragma("unroll")                                                            \
  for (int s = 0; s < 8; s++) {                                                \
    const int k0 = s * 32 + g * 8;                                             \
    const short8v av = *(const short8v*)&base[(OFF) + lr * FCP + k0];          \
    a0 = __builtin_amdgcn_mfma_f32_16x16x32_bf16(                              \
        av, *(const short8v*)&(WT)[(cw +  0 + lr) * 256 + k0], a0, 0, 0, 0);   \
    a1 = __builtin_amdgcn_mfma_f32_16x16x32_bf16(                              \
        av, *(const short8v*)&(WT)[(cw + 16 + lr) * 256 + k0], a1, 0, 0, 0);   \
    a2 = __builtin_amdgcn_mfma_f32_16x16x32_bf16(                              \
        av, *(const short8v*)&(WT)[(cw + 32 + lr) * 256 + k0], a2, 0, 0, 0);   \
    a3 = __builtin_amdgcn_mfma_f32_16x16x32_bf16(                              \
        av, *(const short8v*)&(WT)[(cw + 48 + lr) * 256 + k0], a3, 0, 0, 0);   \
  }

  GEMM8(0, Wt1)

#define STORE_Y(ACC, T)                                                        \
  {                                                                            \
    const int c = cw + 16 * (T) + lr;                                          \
    const float bb = bf1[c];                                                   \
    _Pragma("unroll")                                                          \
    for (int e = 0; e < 4; e++)                                                \
      base[ysoff + (4 * g + e) * FCP + c] = f2b(fmaxf(ACC[e] + bb, 0.f));      \
  }
  STORE_Y(a0, 0) STORE_Y(a1, 1) STORE_Y(a2, 2) STORE_Y(a3, 3)
  __syncthreads();

  a0 = (f32x4){0.f, 0.f, 0.f, 0.f}; a1 = a0; a2 = a0; a3 = a0;
  GEMM8(ysoff, Wt2)
  __syncthreads();

#define STORE_Z(ACC, T)                                                        \
  {                                                                            \
    const int c = cw + 16 * (T) + lr;                                          \
    const float bb = bf2[c];                                                   \
    _Pragma("unroll")                                                          \
    for (int e = 0; e < 4; e++) zs[4 * g + e][c] = ACC[e] + bb;                \
  }
  STORE_Z(a0, 0) STORE_Z(a1, 1) STORE_Z(a2, 2) STORE_Z(a3, 3)
  __syncthreads();

  const int r = tid >> 4, j = tid & 15;
  float s = 0.f;
#pragma unroll
  for (int k2 = 0; k2 < 16; k2++) s += zs[r][j + 16 * k2];
#pragma unroll
  for (int o = 8; o; o >>= 1) s += __shfl_down(s, o, 16);
  if (!j) mu16[r] = s * (1.f / 256.f);
  __syncthreads();
  const float mu = mu16[r];
  float ss = 0.f;
#pragma unroll
  for (int k2 = 0; k2 < 16; k2++) { const float dd = zs[r][j + 16 * k2] - mu; ss += dd * dd; }
#pragma unroll
  for (int o = 8; o; o >>= 1) ss += __shfl_down(ss, o, 16);
  if (!j) rs16[r] = rsqrtf(ss * (1.f / 256.f) + 1e-5f);
  __syncthreads();

  const float gv = g2[tid], bbv = b2p[tid];
#pragma unroll
  for (int rr = 0; rr < FRB; rr++) {
    const size_t o = (r0 + rr) * DOUT + tid;
    const float sk = out[o];
    out[o] = (zs[rr][tid] - mu16[rr]) * rs16[rr] * gv + bbv + sk;
  }
}

extern "C" void kernel_launch(void* const* d_in, const int* in_sizes, int n_in,
                              void* d_out, int out_size, void* d_ws, size_t ws_size,
                              hipStream_t stream) {
  const float* xyz  = (const float*)d_in[0];
  const float* feat = (const float*)d_in[1];
  const float* Wq   = (const float*)d_in[2];
  const float* bq   = (const float*)d_in[3];
  const float* Wk   = (const float*)d_in[4];
  const float* bk   = (const float*)d_in[5];
  const float* Wv   = (const float*)d_in[6];
  const float* bv   = (const float*)d_in[7];
  const float* Wp1  = (const float*)d_in[8];
  const float* bp1  = (const float*)d_in[9];
  const float* Wp2  = (const float*)d_in[10];
  const float* bp2  = (const float*)d_in[11];
  const float* Wf1  = (const float*)d_in[12];
  const float* bf1  = (const float*)d_in[13];
  const float* Wf2  = (const float*)d_in[14];
  const float* bf2  = (const float*)d_in[15];
  const float* g1   = (const float*)d_in[16];
  const float* b1   = (const float*)d_in[17];
  const float* g2   = (const float*)d_in[18];
  const float* b2   = (const float*)d_in[19];

  float* out  = (float*)d_out;
  float* aout = out + (size_t)TOTPTS * DOUT;  // attn-weights output region

  // workspace layout (113 MB peak):
  //   [0, 1 MB)     knn indices u16
  //   [1, 17 MB)    QOA bf16 (proj -> attn-out, ffn input)
  //   [17, 33 MB)   Kf bf16; dead after attn -> reused for Wt1/Wt2 (wprep)
  //   [33, 49 MB)   Vf bf16
  //   [49, 113 MB)  posG bf16
  // AOUT region of d_out doubles as scratch before attn overwrites it:
  //   [0, 512 KB)        xyzw float4 (knn + pos)
  //   [512 KB, 896 KB)   Wq/Wk/Wv split-bf16 transposes (proj B-operands)
  unsigned short* knn  = (unsigned short*)d_ws;
  float4*         xyzw = (float4*)aout;
  bf16* QOA  = (bf16*)((char*)d_ws + (size_t)(1 << 20));
  bf16* Kf   = QOA + (size_t)TOTPTS * DOUT;
  bf16* Vf   = Kf  + (size_t)TOTPTS * DOUT;
  bf16* posG = (bf16*)((char*)d_ws + (size_t)(49 << 20));
  bf16* Wt1  = Kf;                        // ffn weights, alive only after attn
  bf16* Wt2  = Kf + 65536;
  bf16* Wqh  = (bf16*)((char*)aout + (512 << 10));
  bf16* Wql  = Wqh + 32768;
  bf16* Wkh  = Wql + 32768;
  bf16* Wkl  = Wkh + 32768;
  bf16* Wvh  = Wkl + 32768;
  bf16* Wvl  = Wvh + 32768;

  pack_kernel<<<TOTPTS / 256, 256, 0, stream>>>(xyz, xyzw);
  wprep_qkv_kernel<<<48, 256, 0, stream>>>(Wq, Wk, Wv, Wqh, Wql, Wkh, Wkl, Wvh, Wvl);
  knp_fused_kernel<<<TOTPTS / 16 + TOTPTS / PR, 256, 0, stream>>>(
      xyzw, knn, feat, Wqh, Wql, Wkh, Wkl, Wvh, Wvl, bq, bk, bv, g1, b1,
      QOA, Kf, Vf, /*skip->*/out);
  pos_kernel<<<TOTPTS / 4, 256, 0, stream>>>(xyzw, knn, Wp1, bp1, Wp2, bp2, posG);
  attn_kernel<<<TOTPTS, 256, 0, stream>>>(knn, QOA, Kf, Vf, posG, aout);
  wprep_kernel<<<64, 256, 0, stream>>>(Wf1, Wf2, Wt1, Wt2);
  ffn_kernel<<<TOTPTS / FRB, 256, 0, stream>>>(QOA, Wt1, bf1, Wt2, bf2, g2, b2, out);
}

// Round 10
// 674.252 us; speedup vs baseline: 1.6495x; 1.6495x over previous
//
#include <hip/hip_runtime.h>
#include <hip/hip_bf16.h>
#include <math.h>

typedef __hip_bfloat16 bf16;
typedef __attribute__((ext_vector_type(8))) short short8v;   // 8 bf16 = 4 VGPR
typedef __attribute__((ext_vector_type(4))) float f32x4;

#define NBATCH 4
#define NPTS   8192
#define TOTPTS 32768
#define DIM    128
#define DOUT   256
#define KNN    16

__device__ __forceinline__ float b2f(bf16 x) { return __bfloat162float(x); }
__device__ __forceinline__ bf16 f2b(float x) { return __float2bfloat16(x); }

__device__ __forceinline__ float rsum32(float v) {
#pragma unroll
  for (int o = 16; o; o >>= 1) v += __shfl_down(v, o, 32);
  return v;
}

// ---------------------------------------------------------------------------
// Pack xyz -> (x, y, z, |p|^2) float4. xyzw parked in the AOUT region of
// d_out (read by knn/pos, fully overwritten later by attn).
// ---------------------------------------------------------------------------
__global__ __launch_bounds__(256) void pack_kernel(const float* __restrict__ xyz,
                                                   float4* __restrict__ xyzw) {
  const int p = blockIdx.x * 256 + threadIdx.x;
  const float x = xyz[3 * p], y = xyz[3 * p + 1], z = xyz[3 * p + 2];
  xyzw[p] = make_float4(x, y, z, x * x + y * y + z * z);
}

// ---------------------------------------------------------------------------
// Segmented insert for KNN v4 (round-5 proven): top-16 of query S in lanes
// [16S,16S+15], slot = lane&15 ascending. Stable jax.lax.top_k semantics.
// NOTE (round 9 lesson): do NOT co-schedule this kernel with streaming
// kernels -- its xyzw scan set must stay L2-resident (fusion caused 3.5x
// fetch amplification and a 2x total regression).
// ---------------------------------------------------------------------------
template <int S>
__device__ __forceinline__ void ins16(float d2, int g, int lane, int seg,
                                      float& bd, int& bi, float& tmax) {
  unsigned long long mask = __ballot(d2 < tmax);
  while (mask) {                          // wave-uniform loop
    const int l = __builtin_ctzll(mask);
    mask &= mask - 1;
    const float dl = __int_as_float(
        __builtin_amdgcn_readlane(__float_as_int(d2), l));
    if (dl < tmax) {                      // re-check vs tightened threshold
      const int il = g + l;
      const bool keep = bd <= dl;
      const float pd = __shfl_up(bd, 1, 16);    // segmented shift
      const int   pi = __shfl_up(bi, 1, 16);
      const bool fromPrev = ((lane & 15) > 0) && (pd > dl);
      const float nbd = keep ? bd : (fromPrev ? pd : dl);
      const int   nbi = keep ? bi : (fromPrev ? pi : il);
      bd = (seg == S) ? nbd : bd;
      bi = (seg == S) ? nbi : bi;
      tmax = __int_as_float(
          __builtin_amdgcn_readlane(__float_as_int(bd), S * 16 + 15));
    }
  }
}

// ---------------------------------------------------------------------------
// KNN v4 (round-5 proven): 4 queries per wave, segmented top-16 lists.
// ---------------------------------------------------------------------------
__global__ __launch_bounds__(256) void knn_wave_kernel(
    const float4* __restrict__ xyzw, unsigned short* __restrict__ knn_out) {
  const int wid  = threadIdx.x >> 6;
  const int lane = threadIdx.x & 63;
  const int seg  = lane >> 4;
  const int q0 = (blockIdx.x * 4 + wid) * 4;
  const int b = q0 >> 13;
  const float4* cb = xyzw + (size_t)b * NPTS;

  const float4 mA = xyzw[q0 + 0];
  const float4 mB = xyzw[q0 + 1];
  const float4 mC = xyzw[q0 + 2];
  const float4 mD = xyzw[q0 + 3];

  float bd = INFINITY;
  int   bi = 0x7fff;
  float tA = INFINITY, tB = INFINITY, tC = INFINITY, tD = INFINITY;

  for (int g = 0; g < NPTS; g += 64) {
    const float4 t = cb[g + lane];
    const float dA = mA.w + t.w - 2.f * (mA.x * t.x + mA.y * t.y + mA.z * t.z);
    const float dB = mB.w + t.w - 2.f * (mB.x * t.x + mB.y * t.y + mB.z * t.z);
    const float dC = mC.w + t.w - 2.f * (mC.x * t.x + mC.y * t.y + mC.z * t.z);
    const float dD = mD.w + t.w - 2.f * (mD.x * t.x + mD.y * t.y + mD.z * t.z);
    ins16<0>(dA, g, lane, seg, bd, bi, tA);
    ins16<1>(dB, g, lane, seg, bd, bi, tB);
    ins16<2>(dC, g, lane, seg, bd, bi, tC);
    ins16<3>(dD, g, lane, seg, bd, bi, tD);
  }
  knn_out[(size_t)q0 * KNN + lane] = (unsigned short)bi;
}

// ---------------------------------------------------------------------------
// wprep_qkv: transpose Wq/Wk/Wv f32[k][c] -> SPLIT bf16 pairs (hi, lo) in
// MFMA B layout [c][k=128]; ALSO (round 10) Wp2 f32[j][c] -> split bf16
// [c][k=64] for the MFMA pos kernel. Outputs in the AOUT scratch (read-only
// until attn overwrites).
// ---------------------------------------------------------------------------
__global__ __launch_bounds__(256) void wprep_qkv_kernel(
    const float* __restrict__ Wq, const float* __restrict__ Wk,
    const float* __restrict__ Wv, const float* __restrict__ Wp2,
    bf16* __restrict__ Wqh, bf16* __restrict__ Wql,
    bf16* __restrict__ Wkh, bf16* __restrict__ Wkl,
    bf16* __restrict__ Wvh, bf16* __restrict__ Wvl,
    bf16* __restrict__ W2h, bf16* __restrict__ W2l) {
  const int t = blockIdx.x * 256 + threadIdx.x;   // [0, 12800)
  if (t < 12288) {
    const int m = t >> 12;
    const int rem = t & 4095;
    const int c = rem >> 4, k8 = (rem & 15) * 8;
    const float* src = (m == 0) ? Wq : (m == 1) ? Wk : Wv;
    bf16* dh = (m == 0) ? Wqh : (m == 1) ? Wkh : Wvh;
    bf16* dl = (m == 0) ? Wql : (m == 1) ? Wkl : Wvl;
#pragma unroll
    for (int j = 0; j < 8; j++) {
      const float x = src[(k8 + j) * 256 + c];
      const bf16 hi = f2b(x);
      dh[c * 128 + k8 + j] = hi;
      dl[c * 128 + k8 + j] = f2b(x - b2f(hi));
    }
  } else {
    const int rem = t - 12288;                    // [0, 512)
    const int c = rem >> 3, k8 = (rem & 7) * 8;
#pragma unroll
    for (int j = 0; j < 8; j++) {
      const float x = Wp2[(k8 + j) * 64 + c];
      const bf16 hi = f2b(x);
      W2h[c * 64 + k8 + j] = hi;
      W2l[c * 64 + k8 + j] = f2b(x - b2f(hi));
    }
  }
}

// ---------------------------------------------------------------------------
// pos_kernel v2 (round 10): split-bf16 MFMA. Wave = point. h1 = relu(rel@Wp1
// + bp1) is computed DIRECTLY into MFMA A-fragment registers (lane = row
// lr = lane&15 via shfl of rel; k-chunk = s*32 + (lane>>4)*8) -- no LDS.
// pos = h1 @ Wp2 via 24 MFMA (4 col-tiles x 2 k-steps x 3 split terms),
// replacing 1024 VALU FMAs + 256 ds_reads per wave. C/D mapping
// col=lane&15, row=4*(lane>>4)+e (m89-verified). Output posG bf16[p][k][64].
// ---------------------------------------------------------------------------
__global__ __launch_bounds__(256) void pos_kernel(
    const float4* __restrict__ xyzw, const unsigned short* __restrict__ knn_in,
    const float* __restrict__ Wp1, const float* __restrict__ bp1,
    const bf16* __restrict__ W2h, const bf16* __restrict__ W2l,
    const float* __restrict__ bp2,
    bf16* __restrict__ posG) {
  const int wid = threadIdx.x >> 6, lane = threadIdx.x & 63;
  const int p = blockIdx.x * 4 + wid;
  const int b = p >> 13, n = p & (NPTS - 1);
  const float4* cb = xyzw + (size_t)b * NPTS;
  const float4 me = cb[n];

  float rx = 0.f, ry = 0.f, rz = 0.f;
  if (lane < 16) {
    const int idx = knn_in[(size_t)p * KNN + lane];
    const float4 t = cb[idx];
    rx = t.x - me.x; ry = t.y - me.y; rz = t.z - me.z;
  }
  const int g = lane >> 4, lr = lane & 15;
  // this lane's A-row = lr (k-neighbor index); broadcast that row's rel
  const float r0 = __shfl(rx, lr, 64);
  const float r1 = __shfl(ry, lr, 64);
  const float r2 = __shfl(rz, lr, 64);

  // h1 hi/lo A-fragments for the 2 k-steps (j = s*32 + g*8 + i)
  union { short8v v; bf16 e[8]; } ah[2], al[2];
#pragma unroll
  for (int s = 0; s < 2; s++) {
    const int j0 = s * 32 + g * 8;
#pragma unroll
    for (int i = 0; i < 8; i++) {
      const int j = j0 + i;
      const float h = fmaxf(bp1[j] + r0 * Wp1[j] + r1 * Wp1[64 + j]
                                   + r2 * Wp1[128 + j], 0.f);
      const bf16 hh = f2b(h);
      ah[s].e[i] = hh;
      al[s].e[i] = f2b(h - b2f(hh));
    }
  }

  f32x4 acc[4];
#pragma unroll
  for (int t = 0; t < 4; t++) acc[t] = (f32x4){0.f, 0.f, 0.f, 0.f};
#pragma unroll
  for (int s = 0; s < 2; s++) {
    const int k0 = s * 32 + g * 8;
#pragma unroll
    for (int t = 0; t < 4; t++) {
      const int c = 16 * t + lr;
      const short8v bh = *(const short8v*)&W2h[c * 64 + k0];
      const short8v bl = *(const short8v*)&W2l[c * 64 + k0];
      acc[t] = __builtin_amdgcn_mfma_f32_16x16x32_bf16(ah[s].v, bh, acc[t], 0, 0, 0);
      acc[t] = __builtin_amdgcn_mfma_f32_16x16x32_bf16(ah[s].v, bl, acc[t], 0, 0, 0);
      acc[t] = __builtin_amdgcn_mfma_f32_16x16x32_bf16(al[s].v, bh, acc[t], 0, 0, 0);
    }
  }

#pragma unroll
  for (int t = 0; t < 4; t++) {
    const int c = 16 * t + lr;
    const float bb = bp2[c];
#pragma unroll
    for (int e = 0; e < 4; e++) {
      const int row = 4 * g + e;
      posG[((size_t)p * KNN + row) * 64 + c] = f2b(acc[t][e] + bb);
    }
  }
}

// ---------------------------------------------------------------------------
// Projections v2 (round-8 proven): MFMA with split-bf16 operands. 16 rows/
// block, 4 waves; wave w owns cols [64w, 64w+64) as 4 16x16 tiles. Q/K/V/
// skip as ah*bh + ah*bl + al*bh (f32-accurate); Q and skip share Wq B-frags.
// ---------------------------------------------------------------------------
#define PR  16
#define PCP 136
__global__ __launch_bounds__(256) void proj_kernel(
    const float* __restrict__ feat,
    const bf16* __restrict__ Wqh, const bf16* __restrict__ Wql,
    const bf16* __restrict__ Wkh, const bf16* __restrict__ Wkl,
    const bf16* __restrict__ Wvh, const bf16* __restrict__ Wvl,
    const float* __restrict__ bq, const float* __restrict__ bk,
    const float* __restrict__ bv,
    const float* __restrict__ g1, const float* __restrict__ b1,
    bf16* __restrict__ Q, bf16* __restrict__ Kf, bf16* __restrict__ Vf,
    float* __restrict__ skip) {
  __shared__ float fS[PR][DIM];           // 8 KB f32 staging
  __shared__ bf16 fh[PR][PCP], fl[PR][PCP];   // feat hi/lo
  __shared__ bf16 lh[PR][PCP], ll[PR][PCP];   // LN1 hi/lo
  const int tid  = threadIdx.x;
  const size_t r0 = (size_t)blockIdx.x * PR;

  {
    const float4* src = (const float4*)(feat + r0 * DIM);
    float4* dst = (float4*)&fS[0][0];
#pragma unroll
    for (int i = 0; i < 2; i++) dst[tid + i * 256] = src[tid + i * 256];
  }
  __syncthreads();

  {
    const int r = tid >> 4, j = tid & 15;
    float v[8];
    float s = 0.f;
#pragma unroll
    for (int i = 0; i < 8; i++) { v[i] = fS[r][j * 8 + i]; s += v[i]; }
#pragma unroll
    for (int o = 8; o; o >>= 1) s += __shfl_down(s, o, 16);
    const float mu = __shfl(s, 0, 16) * (1.f / 128.f);
    float ss = 0.f;
#pragma unroll
    for (int i = 0; i < 8; i++) { const float d = v[i] - mu; ss += d * d; }
#pragma unroll
    for (int o = 8; o; o >>= 1) ss += __shfl_down(ss, o, 16);
    const float rsd = rsqrtf(__shfl(ss, 0, 16) * (1.f / 128.f) + 1e-5f);
#pragma unroll
    for (int i = 0; i < 8; i++) {
      const int c = j * 8 + i;
      const bf16 hv = f2b(v[i]);
      fh[r][c] = hv;
      fl[r][c] = f2b(v[i] - b2f(hv));
      const float lnv = (v[i] - mu) * rsd * g1[c] + b1[c];
      const bf16 lhv = f2b(lnv);
      lh[r][c] = lhv;
      ll[r][c] = f2b(lnv - b2f(lhv));
    }
  }
  __syncthreads();

  const int w    = tid >> 6;
  const int lane = tid & 63;
  const int g    = lane >> 4, lr = lane & 15;
  const int cw   = w * 64;
  f32x4 qa[4], ka[4], va[4], sa[4];
#pragma unroll
  for (int t = 0; t < 4; t++) {
    qa[t] = (f32x4){0.f, 0.f, 0.f, 0.f};
    ka[t] = qa[t]; va[t] = qa[t]; sa[t] = qa[t];
  }
#pragma unroll
  for (int s = 0; s < 4; s++) {
    const int k0 = s * 32 + g * 8;
    const short8v ah = *(const short8v*)&fh[lr][k0];
    const short8v al = *(const short8v*)&fl[lr][k0];
    const short8v nh = *(const short8v*)&lh[lr][k0];
    const short8v nl = *(const short8v*)&ll[lr][k0];
#pragma unroll
    for (int t = 0; t < 4; t++) {
      const int c = cw + 16 * t + lr;
      const short8v wqh = *(const short8v*)&Wqh[c * 128 + k0];
      const short8v wql = *(const short8v*)&Wql[c * 128 + k0];
      const short8v wkh = *(const short8v*)&Wkh[c * 128 + k0];
      const short8v wkl = *(const short8v*)&Wkl[c * 128 + k0];
      const short8v wvh = *(const short8v*)&Wvh[c * 128 + k0];
      const short8v wvl = *(const short8v*)&Wvl[c * 128 + k0];
      qa[t] = __builtin_amdgcn_mfma_f32_16x16x32_bf16(ah, wqh, qa[t], 0, 0, 0);
      qa[t] = __builtin_amdgcn_mfma_f32_16x16x32_bf16(ah, wql, qa[t], 0, 0, 0);
      qa[t] = __builtin_amdgcn_mfma_f32_16x16x32_bf16(al, wqh, qa[t], 0, 0, 0);
      ka[t] = __builtin_amdgcn_mfma_f32_16x16x32_bf16(ah, wkh, ka[t], 0, 0, 0);
      ka[t] = __builtin_amdgcn_mfma_f32_16x16x32_bf16(ah, wkl, ka[t], 0, 0, 0);
      ka[t] = __builtin_amdgcn_mfma_f32_16x16x32_bf16(al, wkh, ka[t], 0, 0, 0);
      va[t] = __builtin_amdgcn_mfma_f32_16x16x32_bf16(ah, wvh, va[t], 0, 0, 0);
      va[t] = __builtin_amdgcn_mfma_f32_16x16x32_bf16(ah, wvl, va[t], 0, 0, 0);
      va[t] = __builtin_amdgcn_mfma_f32_16x16x32_bf16(al, wvh, va[t], 0, 0, 0);
      sa[t] = __builtin_amdgcn_mfma_f32_16x16x32_bf16(nh, wqh, sa[t], 0, 0, 0);
      sa[t] = __builtin_amdgcn_mfma_f32_16x16x32_bf16(nh, wql, sa[t], 0, 0, 0);
      sa[t] = __builtin_amdgcn_mfma_f32_16x16x32_bf16(nl, wqh, sa[t], 0, 0, 0);
    }
  }

#pragma unroll
  for (int t = 0; t < 4; t++) {
    const int c = cw + 16 * t + lr;
    const float bqv = bq[c], bkv = bk[c], bvv = bv[c];
#pragma unroll
    for (int e = 0; e < 4; e++) {
      const size_t o = (r0 + 4 * g + e) * DOUT + c;
      Q[o]    = f2b(qa[t][e] + bqv);
      Kf[o]   = f2b(ka[t][e] + bkv);
      Vf[o]   = f2b(va[t][e] + bvv);
      skip[o] = sa[t][e] + bqv;
    }
  }
}

// ---------------------------------------------------------------------------
// Attention v3 (round-2 proven).
// ---------------------------------------------------------------------------
__global__ __launch_bounds__(256) void attn_kernel(
    const unsigned short* __restrict__ knn_in,
    bf16* __restrict__ QOA, const bf16* __restrict__ Kf, const bf16* __restrict__ Vf,
    const bf16* __restrict__ posG,
    float* __restrict__ AOUT) {
  __shared__ int nidxS[16];
  const int tid  = threadIdx.x;
  const int w    = tid >> 6;
  const int lane = tid & 63;
  const int p = blockIdx.x;
  const int b = p >> 13, n = p & (NPTS - 1);

  if (tid < 16) nidxS[tid] = knn_in[(size_t)p * KNN + tid];
  const float qreg = b2f(QOA[(size_t)p * DOUT + tid]);
  __syncthreads();

  float kreg[16], vreg[16], posr[16];
  const size_t rowbase = (size_t)b * NPTS;
  const bf16* pg = posG + (size_t)p * KNN * 64 + lane;
#pragma unroll
  for (int k = 0; k < 16; k++) {
    const size_t row = (rowbase + (size_t)nidxS[k]) * DOUT + tid;
    kreg[k] = b2f(Kf[row]);
    vreg[k] = b2f(Vf[row]);
    posr[k] = b2f(pg[k * 64]);
  }

  float lg[16];
#pragma unroll
  for (int k = 0; k < 16; k++) lg[k] = qreg * (kreg[k] + posr[k]);
#pragma unroll
  for (int o = 32; o; o >>= 1) {
#pragma unroll
    for (int k = 0; k < 16; k++) lg[k] += __shfl_xor(lg[k], o, 64);
  }
  float m = -INFINITY;
#pragma unroll
  for (int k = 0; k < 16; k++) { lg[k] *= 0.125f; m = fmaxf(m, lg[k]); }
  float sum = 0.f;
#pragma unroll
  for (int k = 0; k < 16; k++) { lg[k] = expf(lg[k] - m); sum += lg[k]; }
  const float inv = 1.f / sum;
#pragma unroll
  for (int k = 0; k < 16; k++) lg[k] *= inv;
  float av = 0.f;
#pragma unroll
  for (int k = 0; k < 16; k++) if (lane == k) av = lg[k];
  if (lane < 16)
    AOUT[(((size_t)b * 4 + w) * NPTS + n) * KNN + lane] = av;
  float o = 0.f;
#pragma unroll
  for (int k = 0; k < 16; k++) o += lg[k] * (vreg[k] + posr[k]);
  QOA[(size_t)p * DOUT + tid] = f2b(o);
}

// ---------------------------------------------------------------------------
// wprep: one-time transpose+convert Wf1/Wf2 f32[k][c] -> bf16 Wt[c][k].
// ---------------------------------------------------------------------------
__global__ __launch_bounds__(256) void wprep_kernel(
    const float* __restrict__ Wf1, const float* __restrict__ Wf2,
    bf16* __restrict__ Wt1, bf16* __restrict__ Wt2) {
  const int t = blockIdx.x * 256 + threadIdx.x;          // [0, 16384)
  const float* src = (t & 8192) ? Wf2 : Wf1;
  bf16*        dst = (t & 8192) ? Wt2 : Wt1;
  const int rem = t & 8191;
  const int c = rem >> 5, k8 = (rem & 31) * 8;
#pragma unroll
  for (int j = 0; j < 8; j++)
    dst[c * 256 + k8 + j] = f2b(src[(k8 + j) * 256 + c]);
}

// ---------------------------------------------------------------------------
// FFN v4 (round-7 proven): MFMA, 16 rows/block, aliased LDS, LN2 + residual.
// ---------------------------------------------------------------------------
#define FRB 16
#define FCP 264
__global__ __launch_bounds__(256) void ffn_kernel(
    const bf16* __restrict__ OA,
    const bf16* __restrict__ Wt1, const float* __restrict__ bf1,
    const bf16* __restrict__ Wt2, const float* __restrict__ bf2,
    const float* __restrict__ g2, const float* __restrict__ b2p,
    float* __restrict__ out) {
  __shared__ float zs[FRB][FCP];          // 16896 B; aliased as xs|ys (bf16)
  __shared__ float mu16[FRB], rs16[FRB];
  bf16* base = (bf16*)&zs[0][0];
  const int ysoff = FRB * FCP;
  const int tid  = threadIdx.x;
  const int w    = tid >> 6;
  const int lane = tid & 63;
  const int g    = lane >> 4, lr = lane & 15;
  const int cw   = w * 64;
  const size_t r0 = (size_t)blockIdx.x * FRB;

  {
    const short8v* src = (const short8v*)(OA + r0 * DOUT);
#pragma unroll
    for (int i = 0; i < 2; i++) {
      const int ch = tid + i * 256;
      const int row = ch >> 5, c8 = (ch & 31) * 8;
      *(short8v*)&base[row * FCP + c8] = src[ch];
    }
  }
  __syncthreads();

  f32x4 a0 = {0.f, 0.f, 0.f, 0.f}, a1 = a0, a2 = a0, a3 = a0;

#define GEMM8(OFF, WT)                                                         \
  _Pragma("unroll")                                                            \
  for (int s = 0; s < 8; s++) {                                                \
    const int k0 = s * 32 + g * 8;                                             \
    const short8v av = *(const short8v*)&base[(OFF) + lr * FCP + k0];          \
    a0 = __builtin_amdgcn_mfma_f32_16x16x32_bf16(                              \
        av, *(const short8v*)&(WT)[(cw +  0 + lr) * 256 + k0], a0, 0, 0, 0);   \
    a1 = __builtin_amdgcn_mfma_f32_16x16x32_bf16(                              \
        av, *(const short8v*)&(WT)[(cw + 16 + lr) * 256 + k0], a1, 0, 0, 0);   \
    a2 = __builtin_amdgcn_mfma_f32_16x16x32_bf16(                              \
        av, *(const short8v*)&(WT)[(cw + 32 + lr) * 256 + k0], a2, 0, 0, 0);   \
    a3 = __builtin_amdgcn_mfma_f32_16x16x32_bf16(                              \
        av, *(const short8v*)&(WT)[(cw + 48 + lr) * 256 + k0], a3, 0, 0, 0);   \
  }

  GEMM8(0, Wt1)

#define STORE_Y(ACC, T)                                                        \
  {                                                                            \
    const int c = cw + 16 * (T) + lr;                                          \
    const float bb = bf1[c];                                                   \
    _Pragma("unroll")                                                          \
    for (int e = 0; e < 4; e++)                                                \
      base[ysoff + (4 * g + e) * FCP + c] = f2b(fmaxf(ACC[e] + bb, 0.f));      \
  }
  STORE_Y(a0, 0) STORE_Y(a1, 1) STORE_Y(a2, 2) STORE_Y(a3, 3)
  __syncthreads();

  a0 = (f32x4){0.f, 0.f, 0.f, 0.f}; a1 = a0; a2 = a0; a3 = a0;
  GEMM8(ysoff, Wt2)
  __syncthreads();

#define STORE_Z(ACC, T)                                                        \
  {                                                                            \
    const int c = cw + 16 * (T) + lr;                                          \
    const float bb = bf2[c];                                                   \
    _Pragma("unroll")                                                          \
    for (int e = 0; e < 4; e++) zs[4 * g + e][c] = ACC[e] + bb;                \
  }
  STORE_Z(a0, 0) STORE_Z(a1, 1) STORE_Z(a2, 2) STORE_Z(a3, 3)
  __syncthreads();

  const int r = tid >> 4, j = tid & 15;
  float s = 0.f;
#pragma unroll
  for (int k2 = 0; k2 < 16; k2++) s += zs[r][j + 16 * k2];
#pragma unroll
  for (int o = 8; o; o >>= 1) s += __shfl_down(s, o, 16);
  if (!j) mu16[r] = s * (1.f / 256.f);
  __syncthreads();
  const float mu = mu16[r];
  float ss = 0.f;
#pragma unroll
  for (int k2 = 0; k2 < 16; k2++) { const float dd = zs[r][j + 16 * k2] - mu; ss += dd * dd; }
#pragma unroll
  for (int o = 8; o; o >>= 1) ss += __shfl_down(ss, o, 16);
  if (!j) rs16[r] = rsqrtf(ss * (1.f / 256.f) + 1e-5f);
  __syncthreads();

  const float gv = g2[tid], bbv = b2p[tid];
#pragma unroll
  for (int rr = 0; rr < FRB; rr++) {
    const size_t o = (r0 + rr) * DOUT + tid;
    const float sk = out[o];
    out[o] = (zs[rr][tid] - mu16[rr]) * rs16[rr] * gv + bbv + sk;
  }
}

extern "C" void kernel_launch(void* const* d_in, const int* in_sizes, int n_in,
                              void* d_out, int out_size, void* d_ws, size_t ws_size,
                              hipStream_t stream) {
  const float* xyz  = (const float*)d_in[0];
  const float* feat = (const float*)d_in[1];
  const float* Wq   = (const float*)d_in[2];
  const float* bq   = (const float*)d_in[3];
  const float* Wk   = (const float*)d_in[4];
  const float* bk   = (const float*)d_in[5];
  const float* Wv   = (const float*)d_in[6];
  const float* bv   = (const float*)d_in[7];
  const float* Wp1  = (const float*)d_in[8];
  const float* bp1  = (const float*)d_in[9];
  const float* Wp2  = (const float*)d_in[10];
  const float* bp2  = (const float*)d_in[11];
  const float* Wf1  = (const float*)d_in[12];
  const float* bf1  = (const float*)d_in[13];
  const float* Wf2  = (const float*)d_in[14];
  const float* bf2  = (const float*)d_in[15];
  const float* g1   = (const float*)d_in[16];
  const float* b1   = (const float*)d_in[17];
  const float* g2   = (const float*)d_in[18];
  const float* b2   = (const float*)d_in[19];

  float* out  = (float*)d_out;
  float* aout = out + (size_t)TOTPTS * DOUT;  // attn-weights output region

  // workspace layout (113 MB peak):
  //   [0, 1 MB)     knn indices u16
  //   [1, 17 MB)    QOA bf16 (proj -> attn-out, ffn input)
  //   [17, 33 MB)   Kf bf16; dead after attn -> reused for Wt1/Wt2 (wprep)
  //   [33, 49 MB)   Vf bf16
  //   [49, 113 MB)  posG bf16
  // AOUT region of d_out doubles as scratch before attn overwrites it:
  //   [0, 512 KB)        xyzw float4 (knn + pos)
  //   [512 KB, 896 KB)   Wq/Wk/Wv split-bf16 transposes (proj B-operands)
  //   [896 KB, 912 KB)   Wp2 split-bf16 transpose (pos B-operand)
  unsigned short* knn  = (unsigned short*)d_ws;
  float4*         xyzw = (float4*)aout;
  bf16* QOA  = (bf16*)((char*)d_ws + (size_t)(1 << 20));
  bf16* Kf   = QOA + (size_t)TOTPTS * DOUT;
  bf16* Vf   = Kf  + (size_t)TOTPTS * DOUT;
  bf16* posG = (bf16*)((char*)d_ws + (size_t)(49 << 20));
  bf16* Wt1  = Kf;                        // ffn weights, alive only after attn
  bf16* Wt2  = Kf + 65536;
  bf16* Wqh  = (bf16*)((char*)aout + (512 << 10));
  bf16* Wql  = Wqh + 32768;
  bf16* Wkh  = Wql + 32768;
  bf16* Wkl  = Wkh + 32768;
  bf16* Wvh  = Wkl + 32768;
  bf16* Wvl  = Wvh + 32768;
  bf16* W2h  = Wvl + 32768;               // 64x64 split Wp2 (8 KB each)
  bf16* W2l  = W2h + 4096;

  pack_kernel<<<TOTPTS / 256, 256, 0, stream>>>(xyz, xyzw);
  wprep_qkv_kernel<<<50, 256, 0, stream>>>(Wq, Wk, Wv, Wp2,
                                           Wqh, Wql, Wkh, Wkl, Wvh, Wvl,
                                           W2h, W2l);
  knn_wave_kernel<<<TOTPTS / 16, 256, 0, stream>>>(xyzw, knn);
  pos_kernel<<<TOTPTS / 4, 256, 0, stream>>>(xyzw, knn, Wp1, bp1, W2h, W2l, bp2,
                                             posG);
  proj_kernel<<<TOTPTS / PR, 256, 0, stream>>>(feat, Wqh, Wql, Wkh, Wkl, Wvh, Wvl,
                                               bq, bk, bv, g1, b1,
                                               QOA, Kf, Vf, /*skip->*/out);
  attn_kernel<<<TOTPTS, 256, 0, stream>>>(knn, QOA, Kf, Vf, posG, aout);
  wprep_kernel<<<64, 256, 0, stream>>>(Wf1, Wf2, Wt1, Wt2);
  ffn_kernel<<<TOTPTS / FRB, 256, 0, stream>>>(QOA, Wt1, bf1, Wt2, bf2, g2, b2, out);
}

// Round 12
// 655.117 us; speedup vs baseline: 1.6977x; 1.0292x over previous
//
#include <hip/hip_runtime.h>
#include <hip/hip_bf16.h>
#include <math.h>

typedef __hip_bfloat16 bf16;
typedef __attribute__((ext_vector_type(8))) short short8v;   // 8 bf16 = 4 VGPR
typedef __attribute__((ext_vector_type(4))) float f32x4;

#define NBATCH 4
#define NPTS   8192
#define TOTPTS 32768
#define DIM    128
#define DOUT   256
#define KNN    16

__device__ __forceinline__ float b2f(bf16 x) { return __bfloat162float(x); }
__device__ __forceinline__ bf16 f2b(float x) { return __float2bfloat16(x); }

// ---------------------------------------------------------------------------
// Pack xyz -> (x, y, z, |p|^2) float4. xyzw lives in ws scratch (former posG
// region) -- no aliasing with any kernel output.
// ---------------------------------------------------------------------------
__global__ __launch_bounds__(256) void pack_kernel(const float* __restrict__ xyz,
                                                   float4* __restrict__ xyzw) {
  const int p = blockIdx.x * 256 + threadIdx.x;
  const float x = xyz[3 * p], y = xyz[3 * p + 1], z = xyz[3 * p + 2];
  xyzw[p] = make_float4(x, y, z, x * x + y * y + z * z);
}

// ---------------------------------------------------------------------------
// Segmented insert for KNN v4 (round-8 PROVEN body, reverted after round-11
// crash): top-16 of query S in lanes [16S,16S+15], slot = lane&15 ascending.
// Stable jax.lax.top_k tie semantics.
// ---------------------------------------------------------------------------
template <int S>
__device__ __forceinline__ void ins16(float d2, int g, int lane, int seg,
                                      float& bd, int& bi, float& tmax) {
  unsigned long long mask = __ballot(d2 < tmax);
  while (mask) {                          // wave-uniform loop
    const int l = __builtin_ctzll(mask);
    mask &= mask - 1;
    const float dl = __int_as_float(
        __builtin_amdgcn_readlane(__float_as_int(d2), l));
    if (dl < tmax) {                      // re-check vs tightened threshold
      const int il = g + l;
      const bool keep = bd <= dl;
      const float pd = __shfl_up(bd, 1, 16);    // segmented shift
      const int   pi = __shfl_up(bi, 1, 16);
      const bool fromPrev = ((lane & 15) > 0) && (pd > dl);
      const float nbd = keep ? bd : (fromPrev ? pd : dl);
      const int   nbi = keep ? bi : (fromPrev ? pi : il);
      bd = (seg == S) ? nbd : bd;
      bi = (seg == S) ? nbi : bi;
      tmax = __int_as_float(
          __builtin_amdgcn_readlane(__float_as_int(bd), S * 16 + 15));
    }
  }
}

// ---------------------------------------------------------------------------
// KNN v4 (round-5 proven structure): 4 queries per wave, segmented top-16.
// NOTE (round 9 lesson): do NOT co-schedule with streaming kernels -- the
// xyzw scan set must stay L2-resident.
// ---------------------------------------------------------------------------
__global__ __launch_bounds__(256) void knn_wave_kernel(
    const float4* __restrict__ xyzw, unsigned short* __restrict__ knn_out) {
  const int wid  = threadIdx.x >> 6;
  const int lane = threadIdx.x & 63;
  const int seg  = lane >> 4;
  const int q0 = (blockIdx.x * 4 + wid) * 4;
  const int b = q0 >> 13;
  const float4* cb = xyzw + (size_t)b * NPTS;

  const float4 mA = xyzw[q0 + 0];
  const float4 mB = xyzw[q0 + 1];
  const float4 mC = xyzw[q0 + 2];
  const float4 mD = xyzw[q0 + 3];

  float bd = INFINITY;
  int   bi = 0x7fff;
  float tA = INFINITY, tB = INFINITY, tC = INFINITY, tD = INFINITY;

  for (int g = 0; g < NPTS; g += 64) {
    const float4 t = cb[g + lane];
    const float dA = mA.w + t.w - 2.f * (mA.x * t.x + mA.y * t.y + mA.z * t.z);
    const float dB = mB.w + t.w - 2.f * (mB.x * t.x + mB.y * t.y + mB.z * t.z);
    const float dC = mC.w + t.w - 2.f * (mC.x * t.x + mC.y * t.y + mC.z * t.z);
    const float dD = mD.w + t.w - 2.f * (mD.x * t.x + mD.y * t.y + mD.z * t.z);
    ins16<0>(dA, g, lane, seg, bd, bi, tA);
    ins16<1>(dB, g, lane, seg, bd, bi, tB);
    ins16<2>(dC, g, lane, seg, bd, bi, tC);
    ins16<3>(dD, g, lane, seg, bd, bi, tD);
  }
  knn_out[(size_t)q0 * KNN + lane] = (unsigned short)bi;
}

// ---------------------------------------------------------------------------
// wprep_qkv: transpose Wq/Wk/Wv f32[k][c] -> SPLIT bf16 pairs (hi, lo) in
// MFMA B layout [c][k=128]; also Wp2 f32[j][c] -> split bf16 [c][k=64]
// (consumed by the fused pos-MLP inside attn). All outputs in ws scratch.
// ---------------------------------------------------------------------------
__global__ __launch_bounds__(256) void wprep_qkv_kernel(
    const float* __restrict__ Wq, const float* __restrict__ Wk,
    const float* __restrict__ Wv, const float* __restrict__ Wp2,
    bf16* __restrict__ Wqh, bf16* __restrict__ Wql,
    bf16* __restrict__ Wkh, bf16* __restrict__ Wkl,
    bf16* __restrict__ Wvh, bf16* __restrict__ Wvl,
    bf16* __restrict__ W2h, bf16* __restrict__ W2l) {
  const int t = blockIdx.x * 256 + threadIdx.x;   // [0, 12800)
  if (t < 12288) {
    const int m = t >> 12;
    const int rem = t & 4095;
    const int c = rem >> 4, k8 = (rem & 15) * 8;
    const float* src = (m == 0) ? Wq : (m == 1) ? Wk : Wv;
    bf16* dh = (m == 0) ? Wqh : (m == 1) ? Wkh : Wvh;
    bf16* dl = (m == 0) ? Wql : (m == 1) ? Wkl : Wvl;
#pragma unroll
    for (int j = 0; j < 8; j++) {
      const float x = src[(k8 + j) * 256 + c];
      const bf16 hi = f2b(x);
      dh[c * 128 + k8 + j] = hi;
      dl[c * 128 + k8 + j] = f2b(x - b2f(hi));
    }
  } else {
    const int rem = t - 12288;                    // [0, 512)
    const int c = rem >> 3, k8 = (rem & 7) * 8;
#pragma unroll
    for (int j = 0; j < 8; j++) {
      const float x = Wp2[(k8 + j) * 64 + c];
      const bf16 hi = f2b(x);
      W2h[c * 64 + k8 + j] = hi;
      W2l[c * 64 + k8 + j] = f2b(x - b2f(hi));
    }
  }
}

// ---------------------------------------------------------------------------
// Projections v2 (round-8 proven): MFMA with split-bf16 operands. 16 rows/
// block, 4 waves; wave w owns cols [64w, 64w+64) as 4 16x16 tiles.
// ---------------------------------------------------------------------------
#define PR  16
#define PCP 136
__global__ __launch_bounds__(256) void proj_kernel(
    const float* __restrict__ feat,
    const bf16* __restrict__ Wqh, const bf16* __restrict__ Wql,
    const bf16* __restrict__ Wkh, const bf16* __restrict__ Wkl,
    const bf16* __restrict__ Wvh, const bf16* __restrict__ Wvl,
    const float* __restrict__ bq, const float* __restrict__ bk,
    const float* __restrict__ bv,
    const float* __restrict__ g1, const float* __restrict__ b1,
    bf16* __restrict__ Q, bf16* __restrict__ Kf, bf16* __restrict__ Vf,
    float* __restrict__ skip) {
  __shared__ float fS[PR][DIM];           // 8 KB f32 staging
  __shared__ bf16 fh[PR][PCP], fl[PR][PCP];   // feat hi/lo
  __shared__ bf16 lh[PR][PCP], ll[PR][PCP];   // LN1 hi/lo
  const int tid  = threadIdx.x;
  const size_t r0 = (size_t)blockIdx.x * PR;

  {
    const float4* src = (const float4*)(feat + r0 * DIM);
    float4* dst = (float4*)&fS[0][0];
#pragma unroll
    for (int i = 0; i < 2; i++) dst[tid + i * 256] = src[tid + i * 256];
  }
  __syncthreads();

  {
    const int r = tid >> 4, j = tid & 15;
    float v[8];
    float s = 0.f;
#pragma unroll
    for (int i = 0; i < 8; i++) { v[i] = fS[r][j * 8 + i]; s += v[i]; }
#pragma unroll
    for (int o = 8; o; o >>= 1) s += __shfl_down(s, o, 16);
    const float mu = __shfl(s, 0, 16) * (1.f / 128.f);
    float ss = 0.f;
#pragma unroll
    for (int i = 0; i < 8; i++) { const float d = v[i] - mu; ss += d * d; }
#pragma unroll
    for (int o = 8; o; o >>= 1) ss += __shfl_down(ss, o, 16);
    const float rsd = rsqrtf(__shfl(ss, 0, 16) * (1.f / 128.f) + 1e-5f);
#pragma unroll
    for (int i = 0; i < 8; i++) {
      const int c = j * 8 + i;
      const bf16 hv = f2b(v[i]);
      fh[r][c] = hv;
      fl[r][c] = f2b(v[i] - b2f(hv));
      const float lnv = (v[i] - mu) * rsd * g1[c] + b1[c];
      const bf16 lhv = f2b(lnv);
      lh[r][c] = lhv;
      ll[r][c] = f2b(lnv - b2f(lhv));
    }
  }
  __syncthreads();

  const int w    = tid >> 6;
  const int lane = tid & 63;
  const int g    = lane >> 4, lr = lane & 15;
  const int cw   = w * 64;
  f32x4 qa[4], ka[4], va[4], sa[4];
#pragma unroll
  for (int t = 0; t < 4; t++) {
    qa[t] = (f32x4){0.f, 0.f, 0.f, 0.f};
    ka[t] = qa[t]; va[t] = qa[t]; sa[t] = qa[t];
  }
#pragma unroll
  for (int s = 0; s < 4; s++) {
    const int k0 = s * 32 + g * 8;
    const short8v ah = *(const short8v*)&fh[lr][k0];
    const short8v al = *(const short8v*)&fl[lr][k0];
    const short8v nh = *(const short8v*)&lh[lr][k0];
    const short8v nl = *(const short8v*)&ll[lr][k0];
#pragma unroll
    for (int t = 0; t < 4; t++) {
      const int c = cw + 16 * t + lr;
      const short8v wqh = *(const short8v*)&Wqh[c * 128 + k0];
      const short8v wql = *(const short8v*)&Wql[c * 128 + k0];
      const short8v wkh = *(const short8v*)&Wkh[c * 128 + k0];
      const short8v wkl = *(const short8v*)&Wkl[c * 128 + k0];
      const short8v wvh = *(const short8v*)&Wvh[c * 128 + k0];
      const short8v wvl = *(const short8v*)&Wvl[c * 128 + k0];
      qa[t] = __builtin_amdgcn_mfma_f32_16x16x32_bf16(ah, wqh, qa[t], 0, 0, 0);
      qa[t] = __builtin_amdgcn_mfma_f32_16x16x32_bf16(ah, wql, qa[t], 0, 0, 0);
      qa[t] = __builtin_amdgcn_mfma_f32_16x16x32_bf16(al, wqh, qa[t], 0, 0, 0);
      ka[t] = __builtin_amdgcn_mfma_f32_16x16x32_bf16(ah, wkh, ka[t], 0, 0, 0);
      ka[t] = __builtin_amdgcn_mfma_f32_16x16x32_bf16(ah, wkl, ka[t], 0, 0, 0);
      ka[t] = __builtin_amdgcn_mfma_f32_16x16x32_bf16(al, wkh, ka[t], 0, 0, 0);
      va[t] = __builtin_amdgcn_mfma_f32_16x16x32_bf16(ah, wvh, va[t], 0, 0, 0);
      va[t] = __builtin_amdgcn_mfma_f32_16x16x32_bf16(ah, wvl, va[t], 0, 0, 0);
      va[t] = __builtin_amdgcn_mfma_f32_16x16x32_bf16(al, wvh, va[t], 0, 0, 0);
      sa[t] = __builtin_amdgcn_mfma_f32_16x16x32_bf16(nh, wqh, sa[t], 0, 0, 0);
      sa[t] = __builtin_amdgcn_mfma_f32_16x16x32_bf16(nh, wql, sa[t], 0, 0, 0);
      sa[t] = __builtin_amdgcn_mfma_f32_16x16x32_bf16(nl, wqh, sa[t], 0, 0, 0);
    }
  }

#pragma unroll
  for (int t = 0; t < 4; t++) {
    const int c = cw + 16 * t + lr;
    const float bqv = bq[c], bkv = bk[c], bvv = bv[c];
#pragma unroll
    for (int e = 0; e < 4; e++) {
      const size_t o = (r0 + 4 * g + e) * DOUT + c;
      Q[o]    = f2b(qa[t][e] + bqv);
      Kf[o]   = f2b(ka[t][e] + bkv);
      Vf[o]   = f2b(va[t][e] + bvv);
      skip[o] = sa[t][e] + bqv;
    }
  }
}

// ---------------------------------------------------------------------------
// Attention v4b (round 12, hardened): pos-MLP fused in as split-bf16 MFMA,
// computed by WAVE 0 ONLY (waves 1-3 skip to the barrier -- no cross-wave
// same-address LDS writes, 4x less redundant MFMA issue). Deletes the pos
// kernel + 128 MB posG HBM round-trip; posr is f32 (one less rounding).
// K/V gather issues BEFORE the pos compute so HBM latency hides under it.
// ---------------------------------------------------------------------------
__global__ __launch_bounds__(256) void attn_kernel(
    const float4* __restrict__ xyzw, const unsigned short* __restrict__ knn_in,
    bf16* __restrict__ QOA, const bf16* __restrict__ Kf, const bf16* __restrict__ Vf,
    const float* __restrict__ Wp1, const float* __restrict__ bp1,
    const bf16* __restrict__ W2h, const bf16* __restrict__ W2l,
    const float* __restrict__ bp2,
    float* __restrict__ AOUT) {
  __shared__ int nidxS[16];
  __shared__ float posS[16][65];
  const int tid  = threadIdx.x;
  const int w    = tid >> 6;        // wave id = head
  const int lane = tid & 63;        // lane = dim within head
  const int p = blockIdx.x;
  const int b = p >> 13, n = p & (NPTS - 1);

  if (tid < 16) nidxS[tid] = knn_in[(size_t)p * KNN + tid];
  const float qreg = b2f(QOA[(size_t)p * DOUT + tid]);
  __syncthreads();                  // nidxS ready

  // K/V gather into registers (issued early; pos compute hides the latency)
  float kreg[16], vreg[16];
  const size_t rowbase = (size_t)b * NPTS;
#pragma unroll
  for (int k = 0; k < 16; k++) {
    const size_t row = (rowbase + (size_t)nidxS[k]) * DOUT + tid;
    kreg[k] = b2f(Kf[row]);
    vreg[k] = b2f(Vf[row]);
  }

  // ---- fused pos-MLP (split-bf16 MFMA), wave 0 only ----
  if (w == 0) {
    const float4* cb = xyzw + rowbase;
    float rx = 0.f, ry = 0.f, rz = 0.f;
    if (lane < 16) {
      const float4 t = cb[nidxS[lane]];
      const float4 me = cb[n];
      rx = t.x - me.x; ry = t.y - me.y; rz = t.z - me.z;
    }
    const int g = lane >> 4, lr = lane & 15;
    const float r0 = __shfl(rx, lr, 64);
    const float r1 = __shfl(ry, lr, 64);
    const float r2 = __shfl(rz, lr, 64);

    union { short8v v; bf16 e[8]; } ah[2], al[2];
#pragma unroll
    for (int s = 0; s < 2; s++) {
      const int j0 = s * 32 + g * 8;
#pragma unroll
      for (int i = 0; i < 8; i++) {
        const int j = j0 + i;
        const float h = fmaxf(bp1[j] + r0 * Wp1[j] + r1 * Wp1[64 + j]
                                     + r2 * Wp1[128 + j], 0.f);
        const bf16 hh = f2b(h);
        ah[s].e[i] = hh;
        al[s].e[i] = f2b(h - b2f(hh));
      }
    }
    f32x4 acc[4];
#pragma unroll
    for (int t = 0; t < 4; t++) acc[t] = (f32x4){0.f, 0.f, 0.f, 0.f};
#pragma unroll
    for (int s = 0; s < 2; s++) {
      const int k0 = s * 32 + g * 8;
#pragma unroll
      for (int t = 0; t < 4; t++) {
        const int c = 16 * t + lr;
        const short8v bh = *(const short8v*)&W2h[c * 64 + k0];
        const short8v bl = *(const short8v*)&W2l[c * 64 + k0];
        acc[t] = __builtin_amdgcn_mfma_f32_16x16x32_bf16(ah[s].v, bh, acc[t], 0, 0, 0);
        acc[t] = __builtin_amdgcn_mfma_f32_16x16x32_bf16(ah[s].v, bl, acc[t], 0, 0, 0);
        acc[t] = __builtin_amdgcn_mfma_f32_16x16x32_bf16(al[s].v, bh, acc[t], 0, 0, 0);
      }
    }
    // C/D mapping col=lane&15, row=4*(lane>>4)+e (m89-verified)
#pragma unroll
    for (int t = 0; t < 4; t++) {
      const int c = 16 * t + lr;
      const float bb = bp2[c];
#pragma unroll
      for (int e = 0; e < 4; e++) posS[4 * g + e][c] = acc[t][e] + bb;
    }
  }
  __syncthreads();                  // posS ready

  // logits: per-lane partials, butterfly reduce -> all lanes hold all 16
  float posr[16], lg[16];
#pragma unroll
  for (int k = 0; k < 16; k++) {
    posr[k] = posS[k][lane];
    lg[k] = qreg * (kreg[k] + posr[k]);
  }
#pragma unroll
  for (int o = 32; o; o >>= 1) {
#pragma unroll
    for (int k = 0; k < 16; k++) lg[k] += __shfl_xor(lg[k], o, 64);
  }
  float m = -INFINITY;
#pragma unroll
  for (int k = 0; k < 16; k++) { lg[k] *= 0.125f; m = fmaxf(m, lg[k]); }
  float sum = 0.f;
#pragma unroll
  for (int k = 0; k < 16; k++) { lg[k] = expf(lg[k] - m); sum += lg[k]; }
  const float inv = 1.f / sum;
#pragma unroll
  for (int k = 0; k < 16; k++) lg[k] *= inv;
  float av = 0.f;
#pragma unroll
  for (int k = 0; k < 16; k++) if (lane == k) av = lg[k];
  if (lane < 16)
    AOUT[(((size_t)b * 4 + w) * NPTS + n) * KNN + lane] = av;
  float o = 0.f;
#pragma unroll
  for (int k = 0; k < 16; k++) o += lg[k] * (vreg[k] + posr[k]);
  QOA[(size_t)p * DOUT + tid] = f2b(o);
}

// ---------------------------------------------------------------------------
// wprep: one-time transpose+convert Wf1/Wf2 f32[k][c] -> bf16 Wt[c][k].
// ---------------------------------------------------------------------------
__global__ __launch_bounds__(256) void wprep_kernel(
    const float* __restrict__ Wf1, const float* __restrict__ Wf2,
    bf16* __restrict__ Wt1, bf16* __restrict__ Wt2) {
  const int t = blockIdx.x * 256 + threadIdx.x;          // [0, 16384)
  const float* src = (t & 8192) ? Wf2 : Wf1;
  bf16*        dst = (t & 8192) ? Wt2 : Wt1;
  const int rem = t & 8191;
  const int c = rem >> 5, k8 = (rem & 31) * 8;
#pragma unroll
  for (int j = 0; j < 8; j++)
    dst[c * 256 + k8 + j] = f2b(src[(k8 + j) * 256 + c]);
}

// ---------------------------------------------------------------------------
// FFN v4 (round-7 proven): MFMA, 16 rows/block, aliased LDS, LN2 + residual.
// ---------------------------------------------------------------------------
#define FRB 16
#define FCP 264
__global__ __launch_bounds__(256) void ffn_kernel(
    const bf16* __restrict__ OA,
    const bf16* __restrict__ Wt1, const float* __restrict__ bf1,
    const bf16* __restrict__ Wt2, const float* __restrict__ bf2,
    const float* __restrict__ g2, const float* __restrict__ b2p,
    float* __restrict__ out) {
  __shared__ float zs[FRB][FCP];          // 16896 B; aliased as xs|ys (bf16)
  __shared__ float mu16[FRB], rs16[FRB];
  bf16* base = (bf16*)&zs[0][0];
  const int ysoff = FRB * FCP;
  const int tid  = threadIdx.x;
  const int w    = tid >> 6;
  const int lane = tid & 63;
  const int g    = lane >> 4, lr = lane & 15;
  const int cw   = w * 64;
  const size_t r0 = (size_t)blockIdx.x * FRB;

  {
    const short8v* src = (const short8v*)(OA + r0 * DOUT);
#pragma unroll
    for (int i = 0; i < 2; i++) {
      const int ch = tid + i * 256;
      const int row = ch >> 5, c8 = (ch & 31) * 8;
      *(short8v*)&base[row * FCP + c8] = src[ch];
    }
  }
  __syncthreads();

  f32x4 a0 = {0.f, 0.f, 0.f, 0.f}, a1 = a0, a2 = a0, a3 = a0;

#define GEMM8(OFF, WT)                                                         \
  _Pragma("unroll")                                                            \
  for (int s = 0; s < 8; s++) {                                                \
    const int k0 = s * 32 + g * 8;                                             \
    const short8v av = *(const short8v*)&base[(OFF) + lr * FCP + k0];          \
    a0 = __builtin_amdgcn_mfma_f32_16x16x32_bf16(                              \
        av, *(const short8v*)&(WT)[(cw +  0 + lr) * 256 + k0], a0, 0, 0, 0);   \
    a1 = __builtin_amdgcn_mfma_f32_16x16x32_bf16(                              \
        av, *(const short8v*)&(WT)[(cw + 16 + lr) * 256 + k0], a1, 0, 0, 0);   \
    a2 = __builtin_amdgcn_mfma_f32_16x16x32_bf16(                              \
        av, *(const short8v*)&(WT)[(cw + 32 + lr) * 256 + k0], a2, 0, 0, 0);   \
    a3 = __builtin_amdgcn_mfma_f32_16x16x32_bf16(                              \
        av, *(const short8v*)&(WT)[(cw + 48 + lr) * 256 + k0], a3, 0, 0, 0);   \
  }

  GEMM8(0, Wt1)

#define STORE_Y(ACC, T)                                                        \
  {                                                                            \
    const int c = cw + 16 * (T) + lr;                                          \
    const float bb = bf1[c];                                                   \
    _Pragma("unroll")                                                          \
    for (int e = 0; e < 4; e++)                                                \
      base[ysoff + (4 * g + e) * FCP + c] = f2b(fmaxf(ACC[e] + bb, 0.f));      \
  }
  STORE_Y(a0, 0) STORE_Y(a1, 1) STORE_Y(a2, 2) STORE_Y(a3, 3)
  __syncthreads();

  a0 = (f32x4){0.f, 0.f, 0.f, 0.f}; a1 = a0; a2 = a0; a3 = a0;
  GEMM8(ysoff, Wt2)
  __syncthreads();

#define STORE_Z(ACC, T)                                                        \
  {                                                                            \
    const int c = cw + 16 * (T) + lr;                                          \
    const float bb = bf2[c];                                                   \
    _Pragma("unroll")                                                          \
    for (int e = 0; e < 4; e++) zs[4 * g + e][c] = ACC[e] + bb;                \
  }
  STORE_Z(a0, 0) STORE_Z(a1, 1) STORE_Z(a2, 2) STORE_Z(a3, 3)
  __syncthreads();

  const int r = tid >> 4, j = tid & 15;
  float s = 0.f;
#pragma unroll
  for (int k2 = 0; k2 < 16; k2++) s += zs[r][j + 16 * k2];
#pragma unroll
  for (int o = 8; o; o >>= 1) s += __shfl_down(s, o, 16);
  if (!j) mu16[r] = s * (1.f / 256.f);
  __syncthreads();
  const float mu = mu16[r];
  float ss = 0.f;
#pragma unroll
  for (int k2 = 0; k2 < 16; k2++) { const float dd = zs[r][j + 16 * k2] - mu; ss += dd * dd; }
#pragma unroll
  for (int o = 8; o; o >>= 1) ss += __shfl_down(ss, o, 16);
  if (!j) rs16[r] = rsqrtf(ss * (1.f / 256.f) + 1e-5f);
  __syncthreads();

  const float gv = g2[tid], bbv = b2p[tid];
#pragma unroll
  for (int rr = 0; rr < FRB; rr++) {
    const size_t o = (r0 + rr) * DOUT + tid;
    const float sk = out[o];
    out[o] = (zs[rr][tid] - mu16[rr]) * rs16[rr] * gv + bbv + sk;
  }
}

extern "C" void kernel_launch(void* const* d_in, const int* in_sizes, int n_in,
                              void* d_out, int out_size, void* d_ws, size_t ws_size,
                              hipStream_t stream) {
  const float* xyz  = (const float*)d_in[0];
  const float* feat = (const float*)d_in[1];
  const float* Wq   = (const float*)d_in[2];
  const float* bq   = (const float*)d_in[3];
  const float* Wk   = (const float*)d_in[4];
  const float* bk   = (const float*)d_in[5];
  const float* Wv   = (const float*)d_in[6];
  const float* bv   = (const float*)d_in[7];
  const float* Wp1  = (const float*)d_in[8];
  const float* bp1  = (const float*)d_in[9];
  const float* Wp2  = (const float*)d_in[10];
  const float* bp2  = (const float*)d_in[11];
  const float* Wf1  = (const float*)d_in[12];
  const float* bf1  = (const float*)d_in[13];
  const float* Wf2  = (const float*)d_in[14];
  const float* bf2  = (const float*)d_in[15];
  const float* g1   = (const float*)d_in[16];
  const float* b1   = (const float*)d_in[17];
  const float* g2   = (const float*)d_in[18];
  const float* b2   = (const float*)d_in[19];

  float* out  = (float*)d_out;
  float* aout = out + (size_t)TOTPTS * DOUT;  // attn-weights output region

  // workspace layout (~50 MB peak):
  //   [0, 1 MB)       knn indices u16
  //   [1, 17 MB)      QOA bf16 (proj -> attn-out, ffn input)
  //   [17, 33 MB)     Kf bf16; dead after attn -> reused for Wt1/Wt2 (wprep)
  //   [33, 49 MB)     Vf bf16
  //   [49 MB +)       scratch: xyzw float4 (512 KB) | Wq/Wk/Wv split-bf16
  //                   transposes (6 x 64 KB) | Wp2 split (2 x 8 KB)
  unsigned short* knn  = (unsigned short*)d_ws;
  bf16* QOA  = (bf16*)((char*)d_ws + (size_t)(1 << 20));
  bf16* Kf   = QOA + (size_t)TOTPTS * DOUT;
  bf16* Vf   = Kf  + (size_t)TOTPTS * DOUT;
  char* scr  = (char*)d_ws + (size_t)(49 << 20);
  float4* xyzw = (float4*)scr;
  bf16* Wqh  = (bf16*)(scr + (512 << 10));
  bf16* Wql  = Wqh + 32768;
  bf16* Wkh  = Wql + 32768;
  bf16* Wkl  = Wkh + 32768;
  bf16* Wvh  = Wkl + 32768;
  bf16* Wvl  = Wvh + 32768;
  bf16* W2h  = Wvl + 32768;               // 64x64 split Wp2 (8 KB each)
  bf16* W2l  = W2h + 4096;
  bf16* Wt1  = Kf;                        // ffn weights, alive only after attn
  bf16* Wt2  = Kf + 65536;

  pack_kernel<<<TOTPTS / 256, 256, 0, stream>>>(xyz, xyzw);
  wprep_qkv_kernel<<<50, 256, 0, stream>>>(Wq, Wk, Wv, Wp2,
                                           Wqh, Wql, Wkh, Wkl, Wvh, Wvl,
                                           W2h, W2l);
  knn_wave_kernel<<<TOTPTS / 16, 256, 0, stream>>>(xyzw, knn);
  proj_kernel<<<TOTPTS / PR, 256, 0, stream>>>(feat, Wqh, Wql, Wkh, Wkl, Wvh, Wvl,
                                               bq, bk, bv, g1, b1,
                                               QOA, Kf, Vf, /*skip->*/out);
  attn_kernel<<<TOTPTS, 256, 0, stream>>>(xyzw, knn, QOA, Kf, Vf,
                                          Wp1, bp1, W2h, W2l, bp2, aout);
  wprep_kernel<<<64, 256, 0, stream>>>(Wf1, Wf2, Wt1, Wt2);
  ffn_kernel<<<TOTPTS / FRB, 256, 0, stream>>>(QOA, Wt1, bf1, Wt2, bf2, g2, b2, out);
}